// Round 3
// baseline (14.540 us; speedup 1.0000x reference)
//
#include <hip/hip_runtime.h>

namespace {

constexpr int MAXL = 3;
constexpr int NL   = 20;   // len(L_LIST)
constexpr int NC   = 16;   // channels
constexpr int K2   = 3;
constexpr int K3   = 4;
constexpr int NKOUT = 1 + K2 + K3;  // 8 output "l" slots
constexpr int NT2  = 19;
constexpr int NT3  = 189;

constexpr int fact(int k) { return k <= 1 ? 1 : k * fact(k - 1); }

// Mirrors Python _l_list ordering: l ascending, lx descending, ly descending.
constexpr int lindex(int lx, int ly, int lz) {
  int idx = 0;
  for (int l = 0; l <= MAXL; ++l)
    for (int ax = l; ax >= 0; --ax)
      for (int ay = l - ax; ay >= 0; --ay) {
        int az = l - ax - ay;
        if (ax == lx && ay == ly && az == lz) return idx;
        ++idx;
      }
  return -1;
}

struct T2 { int i; int key; float p; };
struct Tab2 { T2 t[NT2]; };
constexpr Tab2 build2() {
  Tab2 o{}; int n = 0; int key = 0;
  for (int l = 1; l <= MAXL; ++l) {
    for (int ax = 0; ax <= l; ++ax)
      for (int ay = 0; ay <= l - ax; ++ay) {
        int az = l - ax - ay;
        int p = fact(l) / (fact(ax) * fact(ay) * fact(az));
        o.t[n].i = lindex(ax, ay, az);
        o.t[n].key = key;
        o.t[n].p = (float)p;
        ++n;
      }
    ++key;
  }
  return o;
}
constexpr Tab2 TAB2 = build2();

struct T3 { int i0, i1, i2, key; float p; };
struct Tab3 { T3 t[NT3]; };
constexpr Tab3 build3() {
  Tab3 o{}; int n = 0; int key = 0;
  for (int k12 = 1; k12 <= MAXL; ++k12)
  for (int k23 = 1; k23 <= MAXL; ++k23)
  for (int k13 = 1; k13 <= MAXL; ++k13) {
    if (k12 + k13 > MAXL || k12 + k23 > MAXL || k23 + k13 > MAXL) continue;
    for (int ax = 0; ax <= k12; ++ax)
    for (int ay = 0; ay <= k12 - ax; ++ay) {
      int az = k12 - ax - ay;
      int pa = fact(k12) / (fact(ax) * fact(ay) * fact(az));
      for (int bx = 0; bx <= k23; ++bx)
      for (int by = 0; by <= k23 - bx; ++by) {
        int bz = k23 - bx - by;
        int pb = fact(k23) / (fact(bx) * fact(by) * fact(bz));
        for (int cx = 0; cx <= k13; ++cx)
        for (int cy = 0; cy <= k13 - cx; ++cy) {
          int cz = k13 - cx - cy;
          int pc = fact(k13) / (fact(cx) * fact(cy) * fact(cz));
          o.t[n].i0 = lindex(ax + cx, ay + cy, az + cz);
          o.t[n].i1 = lindex(ax + bx, ay + by, az + bz);
          o.t[n].i2 = lindex(bx + cx, by + cy, bz + cz);
          o.t[n].key = key;
          o.t[n].p = (float)(pa * pb * pc);
          ++n;
        }
      }
    }
    ++key;
  }
  return o;
}
constexpr Tab3 TAB3 = build3();

typedef float fvec2 __attribute__((ext_vector_type(2)));

} // namespace

// One thread = one (row, channel-pair). 32000*8 = 256k threads = 4096 waves
// = 4 waves/SIMD. Memory ops are dwordx2 (8B/lane): 20 loads + 8 streaming
// stores per thread. 8 consecutive lanes cover one row's 64B line per l.
// Table indices/prefactors fold to compile-time constants.
__global__ __launch_bounds__(256, 4) void symm_kernel(
    const float* __restrict__ in, float* __restrict__ out, int rows) {
  int tid = blockIdx.x * blockDim.x + threadIdx.x;
  if (tid >= rows * (NC / 2)) return;
  int c2 = tid & (NC / 2 - 1);
  long row = tid >> 3;

  const fvec2* __restrict__ inp =
      reinterpret_cast<const fvec2*>(in) + row * (NL * NC / 2) + c2;
  fvec2 a[NL];
#pragma unroll
  for (int l = 0; l < NL; ++l) a[l] = inp[l * (NC / 2)];

  fvec2 acc[NKOUT];
  acc[0] = a[0];  // b1
#pragma unroll
  for (int k = 1; k < NKOUT; ++k) acc[k] = (fvec2)(0.f);

  // nu2: acc[1+key] += p * a[i]^2
#pragma unroll
  for (int t = 0; t < NT2; ++t) {
    const fvec2 v = a[TAB2.t[t].i];
    const float p = TAB2.t[t].p;
    fvec2& d = acc[1 + TAB2.t[t].key];
    d.x = fmaf(p * v.x, v.x, d.x);
    d.y = fmaf(p * v.y, v.y, d.y);
  }

  // nu3: acc[1+K2+key] += p * a[i0]*a[i1]*a[i2]
#pragma unroll
  for (int t = 0; t < NT3; ++t) {
    const fvec2 u = a[TAB3.t[t].i0];
    const fvec2 v = a[TAB3.t[t].i1];
    const fvec2 w = a[TAB3.t[t].i2];
    const float p = TAB3.t[t].p;
    fvec2& d = acc[1 + K2 + TAB3.t[t].key];
    d.x = fmaf(p * (u.x * v.x), w.x, d.x);
    d.y = fmaf(p * (u.y * v.y), w.y, d.y);
  }

  fvec2* __restrict__ op =
      reinterpret_cast<fvec2*>(out) + row * (NKOUT * NC / 2) + c2;
#pragma unroll
  for (int k = 0; k < NKOUT; ++k)
    __builtin_nontemporal_store(acc[k], op + k * (NC / 2));
}

extern "C" void kernel_launch(void* const* d_in, const int* in_sizes, int n_in,
                              void* d_out, int out_size, void* d_ws, size_t ws_size,
                              hipStream_t stream) {
  const float* in = (const float*)d_in[0];
  float* out = (float*)d_out;
  int rows = in_sizes[0] / (NL * NC);       // 4000 * 8 = 32000
  int total = rows * (NC / 2);              // one thread per channel-pair
  int block = 256;
  int grid = (total + block - 1) / block;
  hipLaunchKernelGGL(symm_kernel, dim3(grid), dim3(block), 0, stream,
                     in, out, rows);
}